// Round 2
// baseline (1041.481 us; speedup 1.0000x reference)
//
#include <hip/hip_runtime.h>

#define USER_NUM 100000
#define ITEM_NUM 150000
#define N_NODES  250000      // USER_NUM + ITEM_NUM
#define EMB      64
#define N_LAYERS 3
#define N_EDGES  1200000
#define N_ELEM   (N_NODES * EMB)   // 16,000,000

// ---- bf16 <-> f32 bit helpers (round-to-nearest-even for store) ----
__device__ __forceinline__ float bf2f(unsigned short u) {
    unsigned int x = ((unsigned int)u) << 16;
    return __uint_as_float(x);
}
__device__ __forceinline__ unsigned short f2bf(float f) {
    unsigned int x = __float_as_uint(f);
    unsigned int r = (x + 0x7fffu + ((x >> 16) & 1u)) >> 16;
    return (unsigned short)r;
}

// Detect storage dtype of the float arrays. If they are bf16, the first 64
// ushorts of user_emb all decode to |v| < 16 (data ~N(0,0.1)). If they are
// fp32, even-index ushorts are low-mantissa bits -> random exponents ->
// P(all 64 pass) ~ 2^-64. flag=1 means bf16 storage, 0 means fp32.
__global__ void detect_kernel(const unsigned short* __restrict__ user,
                              int* __restrict__ flag) {
    int lane = threadIdx.x;          // 64 threads = 1 wave
    float v = bf2f(user[lane]);
    bool ok = (v > -16.0f) && (v < 16.0f);   // NaN -> false
    unsigned long long m = __ballot(ok);
    if (lane == 0) flag[0] = (m == ~0ull) ? 1 : 0;
}

// out = embeds (same dtype as input storage); cur = embeds as fp32.
// 4 elements/thread; user/item boundary (6.4M) is 4-aligned.
__global__ void init_kernel(const void* __restrict__ user,
                            const void* __restrict__ item,
                            void* __restrict__ out,
                            float* __restrict__ cur,
                            const int* __restrict__ flag) {
    int i = blockIdx.x * blockDim.x + threadIdx.x;   // vec-4 index
    if (i >= N_ELEM / 4) return;
    int base = i * 4;
    const int UE = USER_NUM * EMB;
    float4 v;
    if (*flag) {  // bf16 storage
        const unsigned short* src = (base < UE)
            ? (const unsigned short*)user + base
            : (const unsigned short*)item + (base - UE);
        ushort4 a = *(const ushort4*)src;
        *(ushort4*)((unsigned short*)out + base) = a;
        v = make_float4(bf2f(a.x), bf2f(a.y), bf2f(a.z), bf2f(a.w));
    } else {      // fp32 storage
        const float* src = (base < UE)
            ? (const float*)user + base
            : (const float*)item + (base - UE);
        v = *(const float4*)src;
        *(float4*)((float*)out + base) = v;
    }
    *(float4*)(cur + base) = v;
}

// One wave (64 lanes) per edge: lane d handles embedding dim d.
// Gather in[cols[e]] (256B coalesced), scatter-atomicAdd to outv[rows[e]].
__global__ void spmm_kernel(const int* __restrict__ rows,
                            const int* __restrict__ cols,
                            const void* __restrict__ vals,
                            const float* __restrict__ in,
                            float* __restrict__ outv,
                            const int* __restrict__ flag) {
    int t = blockIdx.x * blockDim.x + threadIdx.x;
    int e = t >> 6;          // edge index (wave-uniform)
    int d = t & 63;          // embedding dim (lane)
    if (e >= N_EDGES) return;
    int   r = rows[e];
    int   c = cols[e];
    float v = (*flag) ? bf2f(((const unsigned short*)vals)[e])
                      : ((const float*)vals)[e];
    float x = in[c * EMB + d];
    atomicAdd(&outv[r * EMB + d], v * x);
}

// out += cur (out in storage dtype, cur fp32), 4 elements/thread
__global__ void add_kernel(void* __restrict__ out,
                           const float* __restrict__ cur,
                           const int* __restrict__ flag) {
    int i = blockIdx.x * blockDim.x + threadIdx.x;   // vec-4 index
    if (i >= N_ELEM / 4) return;
    float4 c = ((const float4*)cur)[i];
    if (*flag) {  // bf16 out
        ushort4 o = ((const ushort4*)out)[i];
        o.x = f2bf(bf2f(o.x) + c.x);
        o.y = f2bf(bf2f(o.y) + c.y);
        o.z = f2bf(bf2f(o.z) + c.z);
        o.w = f2bf(bf2f(o.w) + c.w);
        ((ushort4*)out)[i] = o;
    } else {      // fp32 out
        float4 o = ((const float4*)out)[i];
        o.x += c.x; o.y += c.y; o.z += c.z; o.w += c.w;
        ((float4*)out)[i] = o;
    }
}

extern "C" void kernel_launch(void* const* d_in, const int* in_sizes, int n_in,
                              void* d_out, int out_size, void* d_ws, size_t ws_size,
                              hipStream_t stream) {
    const void* user = d_in[0];
    const void* item = d_in[1];
    const int*  rows = (const int*)d_in[2];
    const int*  cols = (const int*)d_in[3];
    const void* vals = d_in[4];

    int*   flag  = (int*)d_ws;
    float* cur_a = (float*)((char*)d_ws + 256);   // 64 MB
    float* cur_b = cur_a + N_ELEM;                // 64 MB

    detect_kernel<<<1, 64, 0, stream>>>((const unsigned short*)user, flag);

    {   // init: out = embeds, cur_a = embeds (fp32)
        int threads = N_ELEM / 4;            // 4,000,000
        init_kernel<<<(threads + 255) / 256, 256, 0, stream>>>(user, item, d_out, cur_a, flag);
    }

    for (int layer = 0; layer < N_LAYERS; ++layer) {
        hipMemsetAsync(cur_b, 0, (size_t)N_ELEM * sizeof(float), stream);
        {
            long long threads = (long long)N_EDGES * 64;   // 76.8M
            spmm_kernel<<<(int)((threads + 255) / 256), 256, 0, stream>>>(
                rows, cols, vals, cur_a, cur_b, flag);
        }
        {
            int threads = N_ELEM / 4;        // 4,000,000
            add_kernel<<<(threads + 255) / 256, 256, 0, stream>>>(d_out, cur_b, flag);
        }
        float* tmp = cur_a; cur_a = cur_b; cur_b = tmp;
    }
}

// Round 3
// 607.654 us; speedup vs baseline: 1.7139x; 1.7139x over previous
//
#include <hip/hip_runtime.h>

#define USER_NUM 100000
#define ITEM_NUM 150000
#define N_NODES  250000
#define EMB      64
#define N_LAYERS 3
#define N_EDGES  1200000
#define N_ELEM   (N_NODES * EMB)          // 16,000,000
#define NB       977                       // ceil(N_NODES/256) scan blocks

// ---------------- CSR build ----------------

// histogram of row degrees
__global__ void hist_kernel(const int* __restrict__ rows, int* __restrict__ cnt) {
    int e = blockIdx.x * blockDim.x + threadIdx.x;
    if (e >= N_EDGES) return;
    atomicAdd(&cnt[rows[e]], 1);
}

// per-256-block sums of cnt
__global__ void blocksum_kernel(const int* __restrict__ cnt, int* __restrict__ blk) {
    __shared__ int s[256];
    int i = blockIdx.x * 256 + threadIdx.x;
    s[threadIdx.x] = (i < N_NODES) ? cnt[i] : 0;
    __syncthreads();
    for (int off = 128; off > 0; off >>= 1) {
        if (threadIdx.x < off) s[threadIdx.x] += s[threadIdx.x + off];
        __syncthreads();
    }
    if (threadIdx.x == 0) blk[blockIdx.x] = s[0];
}

// exclusive scan of the NB block sums (single 1024-thread block)
__global__ void scanblk_kernel(int* __restrict__ blk) {
    __shared__ int s[1024];
    int i = threadIdx.x;
    int x = (i < NB) ? blk[i] : 0;
    s[i] = x;
    __syncthreads();
    for (int off = 1; off < 1024; off <<= 1) {
        int t = (i >= off) ? s[i - off] : 0;
        __syncthreads();
        s[i] += t;
        __syncthreads();
    }
    if (i < NB) blk[i] = s[i] - x;   // exclusive
}

// block-local exclusive scan + block base -> row_ptr; also init row_cur
__global__ void rowptr_kernel(const int* __restrict__ cnt, const int* __restrict__ blk,
                              int* __restrict__ row_ptr, int* __restrict__ row_cur) {
    __shared__ int s[256];
    int i = blockIdx.x * 256 + threadIdx.x;
    int x = (i < N_NODES) ? cnt[i] : 0;
    s[threadIdx.x] = x;
    __syncthreads();
    for (int off = 1; off < 256; off <<= 1) {
        int t = (threadIdx.x >= off) ? s[threadIdx.x - off] : 0;
        __syncthreads();
        s[threadIdx.x] += t;
        __syncthreads();
    }
    if (i < N_NODES) {
        int v = blk[blockIdx.x] + s[threadIdx.x] - x;   // global exclusive prefix
        row_ptr[i] = v;
        row_cur[i] = v;
    }
    if (blockIdx.x == 0 && threadIdx.x == 0) row_ptr[N_NODES] = N_EDGES;
}

// scatter edges into CSR order: edges[pos] = (col, val-bits)
__global__ void scatter_kernel(const int* __restrict__ rows, const int* __restrict__ cols,
                               const float* __restrict__ vals,
                               int* __restrict__ row_cur, int2* __restrict__ edges) {
    int e = blockIdx.x * blockDim.x + threadIdx.x;
    if (e >= N_EDGES) return;
    int pos = atomicAdd(&row_cur[rows[e]], 1);
    edges[pos] = make_int2(cols[e], __float_as_int(vals[e]));
}

// ---------------- encoder ----------------

// out = embeds (fp32), cur = embeds (fp32). 4 elems/thread; 6.4M boundary is 4-aligned.
__global__ void init_kernel(const float* __restrict__ user, const float* __restrict__ item,
                            float* __restrict__ out, float* __restrict__ cur) {
    int i = blockIdx.x * blockDim.x + threadIdx.x;
    if (i >= N_ELEM / 4) return;
    int base = i * 4;
    const int UE = USER_NUM * EMB;
    const float4 v = (base < UE) ? *(const float4*)(user + base)
                                 : *(const float4*)(item + (base - UE));
    *(float4*)(out + base) = v;
    *(float4*)(cur + base) = v;
}

// One wave per row: lanes 0..deg-1 vector-load (col,val), shfl-broadcast,
// lane d accumulates v * in[c*64+d]; coalesced 256B store; fused out += acc.
template <int LAST>
__global__ void spmm_fused_kernel(const int* __restrict__ row_ptr,
                                  const int2* __restrict__ edges,
                                  const float* __restrict__ in,
                                  float* __restrict__ cur_out,
                                  float* __restrict__ out) {
    int t = blockIdx.x * blockDim.x + threadIdx.x;
    int r = t >> 6;
    int lane = t & 63;
    if (r >= N_NODES) return;
    int start = row_ptr[r];
    int end   = row_ptr[r + 1];
    float acc = 0.0f;
    for (int base = start; base < end; base += 64) {
        int n = end - base; if (n > 64) n = 64;
        int2 ev = (lane < n) ? edges[base + lane] : make_int2(0, 0);
        for (int j = 0; j < n; ++j) {
            int   c = __shfl(ev.x, j);
            float v = __int_as_float(__shfl(ev.y, j));
            acc += v * in[c * EMB + lane];
        }
    }
    if (!LAST) cur_out[r * EMB + lane] = acc;
    out[r * EMB + lane] += acc;
}

extern "C" void kernel_launch(void* const* d_in, const int* in_sizes, int n_in,
                              void* d_out, int out_size, void* d_ws, size_t ws_size,
                              hipStream_t stream) {
    const float* user = (const float*)d_in[0];
    const float* item = (const float*)d_in[1];
    const int*   rows = (const int*)d_in[2];
    const int*   cols = (const int*)d_in[3];
    const float* vals = (const float*)d_in[4];
    float*       out  = (float*)d_out;

    // workspace layout (256B aligned)
    char* p = (char*)d_ws;
    float* cur_a   = (float*)p;                 p += (size_t)N_ELEM * 4;        // 64 MB
    float* cur_b   = (float*)p;                 p += (size_t)N_ELEM * 4;        // 64 MB
    int*   cnt     = (int*)p;                   p += 1000192;                    // 250000*4 padded
    int*   row_ptr = (int*)p;                   p += 1000192;                    // 250001*4 padded
    int*   row_cur = (int*)p;                   p += 1000192;
    int*   blk     = (int*)p;                   p += 4096;                       // NB*4 padded
    int2*  edges   = (int2*)p;                  /* 9.6 MB */

    // ---- CSR build ----
    hipMemsetAsync(cnt, 0, (size_t)N_NODES * sizeof(int), stream);
    hist_kernel<<<(N_EDGES + 255) / 256, 256, 0, stream>>>(rows, cnt);
    blocksum_kernel<<<NB, 256, 0, stream>>>(cnt, blk);
    scanblk_kernel<<<1, 1024, 0, stream>>>(blk);
    rowptr_kernel<<<NB, 256, 0, stream>>>(cnt, blk, row_ptr, row_cur);
    scatter_kernel<<<(N_EDGES + 255) / 256, 256, 0, stream>>>(rows, cols, vals, row_cur, edges);

    // ---- encoder ----
    init_kernel<<<(N_ELEM / 4 + 255) / 256, 256, 0, stream>>>(user, item, out, cur_a);

    const int spmm_blocks = (N_NODES * 64 + 255) / 256;   // 62500
    spmm_fused_kernel<0><<<spmm_blocks, 256, 0, stream>>>(row_ptr, edges, cur_a, cur_b, out);
    spmm_fused_kernel<0><<<spmm_blocks, 256, 0, stream>>>(row_ptr, edges, cur_b, cur_a, out);
    spmm_fused_kernel<1><<<spmm_blocks, 256, 0, stream>>>(row_ptr, edges, cur_a, cur_b, out);
}

// Round 4
// 485.813 us; speedup vs baseline: 2.1438x; 1.2508x over previous
//
#include <hip/hip_runtime.h>

#define USER_NUM 100000
#define ITEM_NUM 150000
#define N_NODES  250000
#define EMB      64
#define N_LAYERS 3
#define N_EDGES  1200000
#define N_ELEM   (N_NODES * EMB)          // 16,000,000
#define NB       977                       // ceil(N_NODES/256) scan blocks

// ---------------- CSR build ----------------

__global__ void hist_kernel(const int* __restrict__ rows, int* __restrict__ cnt) {
    int e = blockIdx.x * blockDim.x + threadIdx.x;
    if (e >= N_EDGES) return;
    atomicAdd(&cnt[rows[e]], 1);
}

__global__ void blocksum_kernel(const int* __restrict__ cnt, int* __restrict__ blk) {
    __shared__ int s[256];
    int i = blockIdx.x * 256 + threadIdx.x;
    s[threadIdx.x] = (i < N_NODES) ? cnt[i] : 0;
    __syncthreads();
    for (int off = 128; off > 0; off >>= 1) {
        if (threadIdx.x < off) s[threadIdx.x] += s[threadIdx.x + off];
        __syncthreads();
    }
    if (threadIdx.x == 0) blk[blockIdx.x] = s[0];
}

__global__ void scanblk_kernel(int* __restrict__ blk) {
    __shared__ int s[1024];
    int i = threadIdx.x;
    int x = (i < NB) ? blk[i] : 0;
    s[i] = x;
    __syncthreads();
    for (int off = 1; off < 1024; off <<= 1) {
        int t = (i >= off) ? s[i - off] : 0;
        __syncthreads();
        s[i] += t;
        __syncthreads();
    }
    if (i < NB) blk[i] = s[i] - x;   // exclusive
}

__global__ void rowptr_kernel(const int* __restrict__ cnt, const int* __restrict__ blk,
                              int* __restrict__ row_ptr, int* __restrict__ row_cur) {
    __shared__ int s[256];
    int i = blockIdx.x * 256 + threadIdx.x;
    int x = (i < N_NODES) ? cnt[i] : 0;
    s[threadIdx.x] = x;
    __syncthreads();
    for (int off = 1; off < 256; off <<= 1) {
        int t = (threadIdx.x >= off) ? s[threadIdx.x - off] : 0;
        __syncthreads();
        s[threadIdx.x] += t;
        __syncthreads();
    }
    if (i < N_NODES) {
        int v = blk[blockIdx.x] + s[threadIdx.x] - x;
        row_ptr[i] = v;
        row_cur[i] = v;
    }
    if (blockIdx.x == 0 && threadIdx.x == 0) row_ptr[N_NODES] = N_EDGES;
}

__global__ void scatter_kernel(const int* __restrict__ rows, const int* __restrict__ cols,
                               const float* __restrict__ vals,
                               int* __restrict__ row_cur, int2* __restrict__ edges) {
    int e = blockIdx.x * blockDim.x + threadIdx.x;
    if (e >= N_EDGES) return;
    int pos = atomicAdd(&row_cur[rows[e]], 1);
    edges[pos] = make_int2(cols[e], __float_as_int(vals[e]));
}

// ---------------- fused SpMM ----------------
// MODE 0: gather from virtual concat(user,item); out = embeds[r] + acc; cur_out = acc
// MODE 1: gather from cur_in;                    out += acc;            cur_out = acc
// MODE 2: gather from cur_in;                    out += acc             (no cur write)
template <int MODE>
__global__ void spmm_fused_kernel(const int* __restrict__ row_ptr,
                                  const int2* __restrict__ edges,
                                  const float* __restrict__ user,
                                  const float* __restrict__ item,
                                  const float* __restrict__ cur_in,
                                  float* __restrict__ cur_out,
                                  float* __restrict__ out) {
    int t = blockIdx.x * blockDim.x + threadIdx.x;
    int r = t >> 6;
    int lane = t & 63;
    if (r >= N_NODES) return;
    int ru    = __builtin_amdgcn_readfirstlane(r);
    int start = __builtin_amdgcn_readfirstlane(row_ptr[ru]);
    int end   = __builtin_amdgcn_readfirstlane(row_ptr[ru + 1]);

    float acc = 0.0f;
    for (int j = start; j < end; j += 4) {
        // 4 consecutive edge records (32B); reads may run past `end` into the
        // +64B pad — masked below (v=0, c=0).
        int2 e0 = edges[j];
        int2 e1 = edges[j + 1];
        int2 e2 = edges[j + 2];
        int2 e3 = edges[j + 3];
        int   c0 = e0.x;
        int   c1 = (j + 1 < end) ? e1.x : 0;
        int   c2 = (j + 2 < end) ? e2.x : 0;
        int   c3 = (j + 3 < end) ? e3.x : 0;
        float v0 = __int_as_float(e0.y);
        float v1 = (j + 1 < end) ? __int_as_float(e1.y) : 0.0f;
        float v2 = (j + 2 < end) ? __int_as_float(e2.y) : 0.0f;
        float v3 = (j + 3 < end) ? __int_as_float(e3.y) : 0.0f;
        float x0, x1, x2, x3;
        if (MODE == 0) {
            x0 = (c0 < USER_NUM) ? user[c0 * EMB + lane] : item[(c0 - USER_NUM) * EMB + lane];
            x1 = (c1 < USER_NUM) ? user[c1 * EMB + lane] : item[(c1 - USER_NUM) * EMB + lane];
            x2 = (c2 < USER_NUM) ? user[c2 * EMB + lane] : item[(c2 - USER_NUM) * EMB + lane];
            x3 = (c3 < USER_NUM) ? user[c3 * EMB + lane] : item[(c3 - USER_NUM) * EMB + lane];
        } else {
            x0 = cur_in[c0 * EMB + lane];
            x1 = cur_in[c1 * EMB + lane];
            x2 = cur_in[c2 * EMB + lane];
            x3 = cur_in[c3 * EMB + lane];
        }
        acc += v0 * x0;
        acc += v1 * x1;
        acc += v2 * x2;
        acc += v3 * x3;
    }

    int idx = r * EMB + lane;
    if (MODE == 0) {
        float e = (r < USER_NUM) ? user[r * EMB + lane] : item[(r - USER_NUM) * EMB + lane];
        out[idx] = e + acc;
        cur_out[idx] = acc;
    } else if (MODE == 1) {
        out[idx] += acc;
        cur_out[idx] = acc;
    } else {
        out[idx] += acc;
    }
}

extern "C" void kernel_launch(void* const* d_in, const int* in_sizes, int n_in,
                              void* d_out, int out_size, void* d_ws, size_t ws_size,
                              hipStream_t stream) {
    const float* user = (const float*)d_in[0];
    const float* item = (const float*)d_in[1];
    const int*   rows = (const int*)d_in[2];
    const int*   cols = (const int*)d_in[3];
    const float* vals = (const float*)d_in[4];
    float*       out  = (float*)d_out;

    // workspace layout (256B aligned)
    char* p = (char*)d_ws;
    float* cur_a   = (float*)p;  p += (size_t)N_ELEM * 4;     // 64 MB
    float* cur_b   = (float*)p;  p += (size_t)N_ELEM * 4;     // 64 MB
    int*   cnt     = (int*)p;    p += 1000192;                // 250000*4 padded
    int*   row_ptr = (int*)p;    p += 1000192;                // 250001*4 padded
    int*   row_cur = (int*)p;    p += 1000192;
    int*   blk     = (int*)p;    p += 4096;                   // NB*4 padded
    int2*  edges   = (int2*)p;   /* 9.6 MB + 64B pad read-over */

    // ---- CSR build ----
    hipMemsetAsync(cnt, 0, (size_t)N_NODES * sizeof(int), stream);
    hist_kernel<<<(N_EDGES + 255) / 256, 256, 0, stream>>>(rows, cnt);
    blocksum_kernel<<<NB, 256, 0, stream>>>(cnt, blk);
    scanblk_kernel<<<1, 1024, 0, stream>>>(blk);
    rowptr_kernel<<<NB, 256, 0, stream>>>(cnt, blk, row_ptr, row_cur);
    scatter_kernel<<<(N_EDGES + 255) / 256, 256, 0, stream>>>(rows, cols, vals, row_cur, edges);

    // ---- encoder: 3 fused SpMM hops ----
    const int spmm_blocks = (N_NODES * 64 + 255) / 256;   // 62500
    spmm_fused_kernel<0><<<spmm_blocks, 256, 0, stream>>>(row_ptr, edges, user, item, nullptr, cur_a, out);
    spmm_fused_kernel<1><<<spmm_blocks, 256, 0, stream>>>(row_ptr, edges, user, item, cur_a, cur_b, out);
    spmm_fused_kernel<2><<<spmm_blocks, 256, 0, stream>>>(row_ptr, edges, user, item, cur_b, nullptr, out);
}

// Round 5
// 408.650 us; speedup vs baseline: 2.5486x; 1.1888x over previous
//
#include <hip/hip_runtime.h>
#include <hip/hip_fp16.h>

#define USER_NUM 100000
#define ITEM_NUM 150000
#define N_NODES  250000
#define EMB      64
#define N_EDGES  1200000
#define N_ELEM   (N_NODES * EMB)          // 16,000,000
#define NB       977                       // ceil(N_NODES/256) scan blocks

// ---------------- CSR build ----------------

__global__ void hist_kernel(const int* __restrict__ rows, int* __restrict__ cnt) {
    int e = blockIdx.x * blockDim.x + threadIdx.x;
    if (e >= N_EDGES) return;
    atomicAdd(&cnt[rows[e]], 1);
}

__global__ void blocksum_kernel(const int* __restrict__ cnt, int* __restrict__ blk) {
    __shared__ int s[256];
    int i = blockIdx.x * 256 + threadIdx.x;
    s[threadIdx.x] = (i < N_NODES) ? cnt[i] : 0;
    __syncthreads();
    for (int off = 128; off > 0; off >>= 1) {
        if (threadIdx.x < off) s[threadIdx.x] += s[threadIdx.x + off];
        __syncthreads();
    }
    if (threadIdx.x == 0) blk[blockIdx.x] = s[0];
}

__global__ void scanblk_kernel(int* __restrict__ blk) {
    __shared__ int s[1024];
    int i = threadIdx.x;
    int x = (i < NB) ? blk[i] : 0;
    s[i] = x;
    __syncthreads();
    for (int off = 1; off < 1024; off <<= 1) {
        int t = (i >= off) ? s[i - off] : 0;
        __syncthreads();
        s[i] += t;
        __syncthreads();
    }
    if (i < NB) blk[i] = s[i] - x;   // exclusive
}

__global__ void rowptr_kernel(const int* __restrict__ cnt, const int* __restrict__ blk,
                              int* __restrict__ row_ptr, int* __restrict__ row_cur) {
    __shared__ int s[256];
    int i = blockIdx.x * 256 + threadIdx.x;
    int x = (i < N_NODES) ? cnt[i] : 0;
    s[threadIdx.x] = x;
    __syncthreads();
    for (int off = 1; off < 256; off <<= 1) {
        int t = (threadIdx.x >= off) ? s[threadIdx.x - off] : 0;
        __syncthreads();
        s[threadIdx.x] += t;
        __syncthreads();
    }
    if (i < N_NODES) {
        int v = blk[blockIdx.x] + s[threadIdx.x] - x;
        row_ptr[i] = v;
        row_cur[i] = v;
    }
    if (blockIdx.x == 0 && threadIdx.x == 0) row_ptr[N_NODES] = N_EDGES;
}

__global__ void scatter_kernel(const int* __restrict__ rows, const int* __restrict__ cols,
                               const float* __restrict__ vals,
                               int* __restrict__ row_cur, int2* __restrict__ edges) {
    int e = blockIdx.x * blockDim.x + threadIdx.x;
    if (e >= N_EDGES) return;
    int pos = atomicAdd(&row_cur[rows[e]], 1);
    edges[pos] = make_int2(cols[e], __float_as_int(vals[e]));
}

// ---------------- init: fp32 user||item -> fp16 table ----------------
__global__ void init_kernel(const float* __restrict__ user, const float* __restrict__ item,
                            __half* __restrict__ emb16) {
    int i = blockIdx.x * blockDim.x + threadIdx.x;   // vec-4 index
    if (i >= N_ELEM / 4) return;
    int base = i * 4;
    const int UE = USER_NUM * EMB;
    float4 v = (base < UE) ? *(const float4*)(user + base)
                           : *(const float4*)(item + (base - UE));
    __half2 h0 = __float22half2_rn(make_float2(v.x, v.y));
    __half2 h1 = __float22half2_rn(make_float2(v.z, v.w));
    *(__half2*)(emb16 + base)     = h0;
    *(__half2*)(emb16 + base + 2) = h1;
}

// ---------------- fused SpMM ----------------
// Half-wave (32 lanes) per row; lane l owns dims {2l, 2l+1} as half2/float2.
// MODE 0: in=emb16; out = emb32[r] + acc (store); cur_out = acc
// MODE 1: in=cur_in; out += acc; cur_out = acc
// MODE 2: in=cur_in; out += acc
template <int MODE>
__global__ void spmm_fused_kernel(const int* __restrict__ row_ptr,
                                  const int2* __restrict__ edges,
                                  const __half* __restrict__ in16,
                                  const float* __restrict__ user,
                                  const float* __restrict__ item,
                                  float* __restrict__ out,
                                  __half* __restrict__ cur_out) {
    int t = blockIdx.x * blockDim.x + threadIdx.x;
    int r = t >> 5;           // row = half-wave index
    int l = t & 31;
    if (r >= N_NODES) return;
    int start = row_ptr[r];
    int end   = row_ptr[r + 1];

    float accx = 0.0f, accy = 0.0f;
    for (int j = start; j < end; j += 4) {
        // 4 consecutive 8B edge records; overrun past `end` masked (c=0,v=0);
        // edges buffer has a 64B tail pad for the final row.
        int2 e0 = edges[j];
        int2 e1 = edges[j + 1];
        int2 e2 = edges[j + 2];
        int2 e3 = edges[j + 3];
        int   c0 = e0.x;
        int   c1 = (j + 1 < end) ? e1.x : 0;
        int   c2 = (j + 2 < end) ? e2.x : 0;
        int   c3 = (j + 3 < end) ? e3.x : 0;
        float v0 = __int_as_float(e0.y);
        float v1 = (j + 1 < end) ? __int_as_float(e1.y) : 0.0f;
        float v2 = (j + 2 < end) ? __int_as_float(e2.y) : 0.0f;
        float v3 = (j + 3 < end) ? __int_as_float(e3.y) : 0.0f;
        float2 x0 = __half22float2(*(const __half2*)(in16 + c0 * EMB + 2 * l));
        float2 x1 = __half22float2(*(const __half2*)(in16 + c1 * EMB + 2 * l));
        float2 x2 = __half22float2(*(const __half2*)(in16 + c2 * EMB + 2 * l));
        float2 x3 = __half22float2(*(const __half2*)(in16 + c3 * EMB + 2 * l));
        accx += v0 * x0.x; accy += v0 * x0.y;
        accx += v1 * x1.x; accy += v1 * x1.y;
        accx += v2 * x2.x; accy += v2 * x2.y;
        accx += v3 * x3.x; accy += v3 * x3.y;
    }

    int idx = r * EMB + 2 * l;
    if (MODE == 0) {
        const float* src = (r < USER_NUM) ? user + r * EMB : item + (r - USER_NUM) * EMB;
        float2 e = *(const float2*)(src + 2 * l);
        *(float2*)(out + idx) = make_float2(e.x + accx, e.y + accy);
        *(__half2*)(cur_out + idx) = __float22half2_rn(make_float2(accx, accy));
    } else if (MODE == 1) {
        float2 o = *(const float2*)(out + idx);
        *(float2*)(out + idx) = make_float2(o.x + accx, o.y + accy);
        *(__half2*)(cur_out + idx) = __float22half2_rn(make_float2(accx, accy));
    } else {
        float2 o = *(const float2*)(out + idx);
        *(float2*)(out + idx) = make_float2(o.x + accx, o.y + accy);
    }
}

extern "C" void kernel_launch(void* const* d_in, const int* in_sizes, int n_in,
                              void* d_out, int out_size, void* d_ws, size_t ws_size,
                              hipStream_t stream) {
    const float* user = (const float*)d_in[0];
    const float* item = (const float*)d_in[1];
    const int*   rows = (const int*)d_in[2];
    const int*   cols = (const int*)d_in[3];
    const float* vals = (const float*)d_in[4];
    float*       out  = (float*)d_out;

    // workspace layout (256B aligned): 3x fp16 node tables + CSR arrays + edges
    char* p = (char*)d_ws;
    __half* emb16   = (__half*)p;  p += (size_t)N_ELEM * 2;   // 32 MB
    __half* cur_a   = (__half*)p;  p += (size_t)N_ELEM * 2;   // 32 MB
    __half* cur_b   = (__half*)p;  p += (size_t)N_ELEM * 2;   // 32 MB
    int*    cnt     = (int*)p;     p += 1000192;              // 250000*4 padded
    int*    row_ptr = (int*)p;     p += 1000192;              // 250001*4 padded
    int*    row_cur = (int*)p;     p += 1000192;
    int*    blk     = (int*)p;     p += 4096;                 // NB*4 padded
    int2*   edges   = (int2*)p;    /* 9.6 MB + 64B tail pad for ILP-4 overrun */

    // ---- CSR build ----
    hipMemsetAsync(cnt, 0, (size_t)N_NODES * sizeof(int), stream);
    hist_kernel<<<(N_EDGES + 255) / 256, 256, 0, stream>>>(rows, cnt);
    blocksum_kernel<<<NB, 256, 0, stream>>>(cnt, blk);
    scanblk_kernel<<<1, 1024, 0, stream>>>(blk);
    rowptr_kernel<<<NB, 256, 0, stream>>>(cnt, blk, row_ptr, row_cur);
    scatter_kernel<<<(N_EDGES + 255) / 256, 256, 0, stream>>>(rows, cols, vals, row_cur, edges);

    // ---- fp16 embed table ----
    init_kernel<<<(N_ELEM / 4 + 255) / 256, 256, 0, stream>>>(user, item, emb16);

    // ---- encoder: 3 fused SpMM hops (half-wave per row) ----
    const int spmm_blocks = (N_NODES * 32 + 255) / 256;   // 31250
    spmm_fused_kernel<0><<<spmm_blocks, 256, 0, stream>>>(row_ptr, edges, emb16, user, item, out, cur_a);
    spmm_fused_kernel<1><<<spmm_blocks, 256, 0, stream>>>(row_ptr, edges, cur_a, user, item, out, cur_b);
    spmm_fused_kernel<2><<<spmm_blocks, 256, 0, stream>>>(row_ptr, edges, cur_b, user, item, out, nullptr);
}

// Round 6
// 322.488 us; speedup vs baseline: 3.2295x; 1.2672x over previous
//
#include <hip/hip_runtime.h>
#include <hip/hip_fp16.h>

#define USER_NUM 100000
#define ITEM_NUM 150000
#define N_NODES  250000
#define EMB      64
#define N_EDGES  1200000
#define N_ELEM   (N_NODES * EMB)   // 16,000,000

#define NBLK1 256                  // phase-1 blocks
#define NBUCK 245                  // ceil(N_NODES/1024) buckets of 1024 rows
#define CAP   8192                 // records per bucket region in tmp (stat bound ~7057)
#define TB1   6528                 // phase-1 tile buffer (max padded 4688+245*7=6403)

// ---------------- phase 1: bin edges into 1024-row buckets ----------------
// Emits only full 64B-aligned chunk writes (8 records); chunk tails padded
// with dummy records (x = -1). Accumulates real per-bucket counts.
__global__ __launch_bounds__(256) void bin_kernel(
    const int* __restrict__ rows, const int* __restrict__ cols,
    const float* __restrict__ vals,
    int* __restrict__ chunkcur, int* __restrict__ bucket_cnt,
    int2* __restrict__ tmp)
{
    __shared__ int  scnt[256];     // per-bucket count, later placement cursor
    __shared__ int  spref[256];    // padded exclusive prefix (246 used)
    __shared__ int  schunk[NBUCK]; // global chunk base per bucket
    __shared__ int2 tilebuf[TB1];

    int b = blockIdx.x, t = threadIdx.x;
    int e0 = (int)((long long)b * N_EDGES / NBLK1);
    int e1 = (int)((long long)(b + 1) * N_EDGES / NBLK1);

    scnt[t] = 0;
    __syncthreads();
    // pass A: bucket histogram
    for (int e = e0 + t; e < e1; e += 256)
        atomicAdd(&scnt[rows[e] >> 10], 1);
    __syncthreads();
    int realc = (t < NBUCK) ? scnt[t] : 0;
    int v     = (realc + 7) & ~7;            // padded to 8-record chunks
    __syncthreads();
    spref[t] = v;
    __syncthreads();
    for (int off = 1; off < 256; off <<= 1) {  // inclusive scan
        int u = (t >= off) ? spref[t - off] : 0;
        __syncthreads();
        spref[t] += u;
        __syncthreads();
    }
    int excl = spref[t] - v;
    __syncthreads();
    spref[t] = excl;                          // exclusive; spref[245] = total
    __syncthreads();
    int padded_total = spref[NBUCK];
    if (t < NBUCK) {
        schunk[t] = (v > 0) ? atomicAdd(&chunkcur[t], v >> 3) : 0;
        if (realc > 0) atomicAdd(&bucket_cnt[t], realc);
    }
    __syncthreads();
    scnt[t] = spref[t];                       // placement cursor
    for (int j = t; j < padded_total; j += 256)
        tilebuf[j] = make_int2(-1, 0);        // dummy sentinel
    __syncthreads();
    // pass B: place records grouped by bucket in LDS
    for (int e = e0 + t; e < e1; e += 256) {
        int r  = rows[e];
        int bk = r >> 10;
        int lp = atomicAdd(&scnt[bk], 1);
        tilebuf[lp] = make_int2(((r & 1023) << 18) | cols[e], __float_as_int(vals[e]));
    }
    __syncthreads();
    // pass C: flush padded stream — consecutive threads -> consecutive dests,
    // every group a whole number of 64B-aligned chunks
    for (int j = t; j < padded_total; j += 256) {
        int lo = 0, hi = NBUCK;               // spref[lo] <= j < spref[hi]
        while (hi - lo > 1) {
            int mid = (lo + hi) >> 1;
            if (spref[mid] <= j) lo = mid; else hi = mid;
        }
        tmp[(size_t)lo * CAP + schunk[lo] * 8 + (j - spref[lo])] = tilebuf[j];
    }
}

// ---------------- scan of 245 bucket counts -> bucket_base ----------------
__global__ void scan245_kernel(const int* __restrict__ bucket_cnt,
                               int* __restrict__ bucket_base,
                               int* __restrict__ row_ptr)
{
    __shared__ int s[256];
    int t = threadIdx.x;
    int v = (t < NBUCK) ? bucket_cnt[t] : 0;
    s[t] = v;
    __syncthreads();
    for (int off = 1; off < 256; off <<= 1) {
        int u = (t >= off) ? s[t - off] : 0;
        __syncthreads();
        s[t] += u;
        __syncthreads();
    }
    if (t <= NBUCK) bucket_base[t] = s[t] - v;   // exclusive; [245] = total
    if (t == 0) row_ptr[N_NODES] = N_EDGES;
}

// ---------------- phase 2: exact CSR placement per bucket ----------------
// One block per bucket: hist+scan 1024 rows in LDS (also emits row_ptr slice),
// place records into LDS at exact local positions, stream out coalesced.
__global__ __launch_bounds__(256) void place_kernel(
    const int* __restrict__ chunkcur, const int* __restrict__ bucket_base,
    const int2* __restrict__ tmp,
    int* __restrict__ row_ptr, int2* __restrict__ edges)
{
    __shared__ int  shist[1024];
    __shared__ int  swave[256];
    __shared__ int2 sstage[CAP];   // 64KB

    int b = blockIdx.x, t = threadIdx.x;
    int nrec = chunkcur[b] * 8;
    const int2* src = tmp + (size_t)b * CAP;

    for (int i = t; i < 1024; i += 256) shist[i] = 0;
    __syncthreads();
    for (int j = t; j < nrec; j += 256) {
        int x = src[j].x;
        if (x != -1) atomicAdd(&shist[x >> 18], 1);
    }
    __syncthreads();
    // exclusive scan of 1024 entries (4 per thread)
    int h0 = shist[4 * t], h1 = shist[4 * t + 1], h2 = shist[4 * t + 2], h3 = shist[4 * t + 3];
    int sum = h0 + h1 + h2 + h3;
    swave[t] = sum;
    __syncthreads();
    for (int off = 1; off < 256; off <<= 1) {
        int u = (t >= off) ? swave[t - off] : 0;
        __syncthreads();
        swave[t] += u;
        __syncthreads();
    }
    int base = swave[t] - sum;
    __syncthreads();
    shist[4 * t]     = base;
    shist[4 * t + 1] = base + h0;
    shist[4 * t + 2] = base + h0 + h1;
    shist[4 * t + 3] = base + h0 + h1 + h2;
    __syncthreads();
    int bb = bucket_base[b];
    for (int i = t; i < 1024; i += 256) {
        int idx = b * 1024 + i;
        if (idx < N_NODES) row_ptr[idx] = bb + shist[i];
    }
    __syncthreads();
    for (int j = t; j < nrec; j += 256) {
        int2 rec = src[j];
        if (rec.x != -1) {
            int lp = atomicAdd(&shist[rec.x >> 18], 1);
            sstage[lp] = make_int2(rec.x & 0x3FFFF, rec.y);
        }
    }
    __syncthreads();
    int cnt = bucket_base[b + 1] - bb;
    for (int j = t; j < cnt; j += 256)
        edges[bb + j] = sstage[j];
}

// ---------------- init: fp32 user||item -> fp16 table ----------------
__global__ void init_kernel(const float* __restrict__ user, const float* __restrict__ item,
                            __half* __restrict__ emb16) {
    int i = blockIdx.x * blockDim.x + threadIdx.x;
    if (i >= N_ELEM / 4) return;
    int base = i * 4;
    const int UE = USER_NUM * EMB;
    float4 v = (base < UE) ? *(const float4*)(user + base)
                           : *(const float4*)(item + (base - UE));
    *(__half2*)(emb16 + base)     = __float22half2_rn(make_float2(v.x, v.y));
    *(__half2*)(emb16 + base + 2) = __float22half2_rn(make_float2(v.z, v.w));
}

// ---------------- fused SpMM ----------------
// Half-wave per row. MODE 0: cur_out = acc (fp16). MODE 1 (last layer):
// out = emb16[r] + cur1[r] + in16[r] + acc  (fp32 store, no RMW).
template <int MODE>
__global__ void spmm_kernel(const int* __restrict__ row_ptr,
                            const int2* __restrict__ edges,
                            const __half* __restrict__ in16,
                            const __half* __restrict__ emb16,
                            const __half* __restrict__ cur1,
                            float* __restrict__ out,
                            __half* __restrict__ cur_out) {
    int t = blockIdx.x * blockDim.x + threadIdx.x;
    int r = t >> 5;
    int l = t & 31;
    if (r >= N_NODES) return;
    int start = row_ptr[r];
    int end   = row_ptr[r + 1];

    float accx = 0.0f, accy = 0.0f;
    for (int j = start; j < end; j += 4) {
        int2 e0 = edges[j];
        int2 e1 = edges[j + 1];
        int2 e2 = edges[j + 2];
        int2 e3 = edges[j + 3];
        int   c0 = e0.x;
        int   c1 = (j + 1 < end) ? e1.x : 0;
        int   c2 = (j + 2 < end) ? e2.x : 0;
        int   c3 = (j + 3 < end) ? e3.x : 0;
        float v0 = __int_as_float(e0.y);
        float v1 = (j + 1 < end) ? __int_as_float(e1.y) : 0.0f;
        float v2 = (j + 2 < end) ? __int_as_float(e2.y) : 0.0f;
        float v3 = (j + 3 < end) ? __int_as_float(e3.y) : 0.0f;
        float2 x0 = __half22float2(*(const __half2*)(in16 + c0 * EMB + 2 * l));
        float2 x1 = __half22float2(*(const __half2*)(in16 + c1 * EMB + 2 * l));
        float2 x2 = __half22float2(*(const __half2*)(in16 + c2 * EMB + 2 * l));
        float2 x3 = __half22float2(*(const __half2*)(in16 + c3 * EMB + 2 * l));
        accx += v0 * x0.x; accy += v0 * x0.y;
        accx += v1 * x1.x; accy += v1 * x1.y;
        accx += v2 * x2.x; accy += v2 * x2.y;
        accx += v3 * x3.x; accy += v3 * x3.y;
    }

    int idx = r * EMB + 2 * l;
    if (MODE == 0) {
        *(__half2*)(cur_out + idx) = __float22half2_rn(make_float2(accx, accy));
    } else {
        float2 a = __half22float2(*(const __half2*)(emb16 + idx));
        float2 c1v = __half22float2(*(const __half2*)(cur1 + idx));
        float2 c2v = __half22float2(*(const __half2*)(in16 + idx));
        *(float2*)(out + idx) = make_float2(a.x + c1v.x + c2v.x + accx,
                                            a.y + c1v.y + c2v.y + accy);
    }
}

extern "C" void kernel_launch(void* const* d_in, const int* in_sizes, int n_in,
                              void* d_out, int out_size, void* d_ws, size_t ws_size,
                              hipStream_t stream) {
    const float* user = (const float*)d_in[0];
    const float* item = (const float*)d_in[1];
    const int*   rows = (const int*)d_in[2];
    const int*   cols = (const int*)d_in[3];
    const float* vals = (const float*)d_in[4];
    float*       out  = (float*)d_out;

    // workspace layout (256B aligned), ~122 MB total
    char* p = (char*)d_ws;
    __half* emb16    = (__half*)p;  p += (size_t)N_ELEM * 2;            // 32 MB
    __half* cur1     = (__half*)p;  p += (size_t)N_ELEM * 2;            // 32 MB
    __half* cur2     = (__half*)p;  p += (size_t)N_ELEM * 2;            // 32 MB
    int2*   tmp      = (int2*)p;    p += (size_t)NBUCK * CAP * 8;       // 15.3 MB
    int2*   edges    = (int2*)p;    p += (size_t)N_EDGES * 8 + 256;     // 9.6 MB + pad
    int*    row_ptr  = (int*)p;     p += 1000448;                       // 250001*4 padded
    int*    bucket_base = (int*)p;  p += 1024;                          // 246*4
    int*    bucket_cnt  = (int*)p;  p += 1024;                          // 245*4 (memset)
    int*    chunkcur    = (int*)p;  p += 1024;                          // 245*4 (memset)

    hipMemsetAsync(bucket_cnt, 0, 2048, stream);   // bucket_cnt + chunkcur

    init_kernel<<<(N_ELEM / 4 + 255) / 256, 256, 0, stream>>>(user, item, emb16);
    bin_kernel<<<NBLK1, 256, 0, stream>>>(rows, cols, vals, chunkcur, bucket_cnt, tmp);
    scan245_kernel<<<1, 256, 0, stream>>>(bucket_cnt, bucket_base, row_ptr);
    place_kernel<<<NBUCK, 256, 0, stream>>>(chunkcur, bucket_base, tmp, row_ptr, edges);

    const int spmm_blocks = (N_NODES * 32 + 255) / 256;   // 31250
    spmm_kernel<0><<<spmm_blocks, 256, 0, stream>>>(row_ptr, edges, emb16, emb16, cur1, out, cur1);
    spmm_kernel<0><<<spmm_blocks, 256, 0, stream>>>(row_ptr, edges, cur1, emb16, cur1, out, cur2);
    spmm_kernel<1><<<spmm_blocks, 256, 0, stream>>>(row_ptr, edges, cur2, emb16, cur1, out, nullptr);
}

// Round 7
// 282.236 us; speedup vs baseline: 3.6901x; 1.1426x over previous
//
#include <hip/hip_runtime.h>
#include <hip/hip_fp16.h>

#define USER_NUM 100000
#define ITEM_NUM 150000
#define N_NODES  250000
#define EMB      64
#define N_EDGES  1200000
#define N_ELEM   (N_NODES * EMB)   // 16,000,000

#define NBLK1 512                  // phase-1 blocks
#define NBUCK 245                  // ceil(N_NODES/1024) buckets of 1024 rows
#define CAP   8192                 // records per bucket region in tmp
#define TB1   4096                 // phase-1 tile buffer (max padded 2344+245*7=4059)
#define INIT_BLOCKS 3907           // ceil(N_ELEM/16 / 256)

// ---------------- phase 1: bin edges into 1024-row buckets ----------------
__global__ __launch_bounds__(256) void bin_kernel(
    const int* __restrict__ rows, const int* __restrict__ cols,
    const float* __restrict__ vals,
    int* __restrict__ chunkcur, int* __restrict__ bucket_cnt,
    int2* __restrict__ tmp)
{
    __shared__ int  scnt[256];     // per-bucket count, later placement cursor
    __shared__ int  spref[256];    // padded exclusive prefix (246 used)
    __shared__ int  schunk[NBUCK]; // global chunk base per bucket
    __shared__ int2 tilebuf[TB1];

    int b = blockIdx.x, t = threadIdx.x;
    int e0 = (int)((long long)b * N_EDGES / NBLK1);
    int e1 = (int)((long long)(b + 1) * N_EDGES / NBLK1);

    scnt[t] = 0;
    __syncthreads();
    for (int e = e0 + t; e < e1; e += 256)
        atomicAdd(&scnt[rows[e] >> 10], 1);
    __syncthreads();
    int realc = (t < NBUCK) ? scnt[t] : 0;
    int v     = (realc + 7) & ~7;            // pad to 8-record chunks
    __syncthreads();
    spref[t] = v;
    __syncthreads();
    for (int off = 1; off < 256; off <<= 1) {
        int u = (t >= off) ? spref[t - off] : 0;
        __syncthreads();
        spref[t] += u;
        __syncthreads();
    }
    int excl = spref[t] - v;
    __syncthreads();
    spref[t] = excl;                          // exclusive; spref[245]=total
    __syncthreads();
    int padded_total = spref[NBUCK];
    if (t < NBUCK) {
        schunk[t] = (v > 0) ? atomicAdd(&chunkcur[t], v >> 3) : 0;
        if (realc > 0) atomicAdd(&bucket_cnt[t], realc);
    }
    __syncthreads();
    scnt[t] = spref[t];
    for (int j = t; j < padded_total; j += 256)
        tilebuf[j] = make_int2(-1, 0);
    __syncthreads();
    for (int e = e0 + t; e < e1; e += 256) {
        int r  = rows[e];
        int lp = atomicAdd(&scnt[r >> 10], 1);
        tilebuf[lp] = make_int2(((r & 1023) << 18) | cols[e], __float_as_int(vals[e]));
    }
    __syncthreads();
    // flush: every bucket group a whole number of 64B-aligned chunks
    for (int j = t; j < padded_total; j += 256) {
        int lo = 0, hi = NBUCK;
        while (hi - lo > 1) {
            int mid = (lo + hi) >> 1;
            if (spref[mid] <= j) lo = mid; else hi = mid;
        }
        tmp[(size_t)lo * CAP + schunk[lo] * 8 + (j - spref[lo])] = tilebuf[j];
    }
}

// ---------------- scan of 245 bucket counts ----------------
__global__ void scan245_kernel(const int* __restrict__ bucket_cnt,
                               int* __restrict__ bucket_base,
                               int* __restrict__ row_ptr)
{
    __shared__ int s[256];
    int t = threadIdx.x;
    int v = (t < NBUCK) ? bucket_cnt[t] : 0;
    s[t] = v;
    __syncthreads();
    for (int off = 1; off < 256; off <<= 1) {
        int u = (t >= off) ? s[t - off] : 0;
        __syncthreads();
        s[t] += u;
        __syncthreads();
    }
    if (t <= NBUCK) bucket_base[t] = s[t] - v;
    if (t == 0) row_ptr[N_NODES] = N_EDGES;
}

// ------- phase 2 (fused): blocks [0,NBUCK) place CSR; rest do fp16 init -------
__global__ __launch_bounds__(256) void place_init_kernel(
    const int* __restrict__ chunkcur, const int* __restrict__ bucket_base,
    const int2* __restrict__ tmp,
    int* __restrict__ row_ptr, int2* __restrict__ edges,
    const float* __restrict__ user, const float* __restrict__ item,
    __half* __restrict__ emb16)
{
    __shared__ int  shist[1024];
    __shared__ int  swave[256];
    __shared__ int2 sstage[CAP];   // 64KB

    int t = threadIdx.x;
    if (blockIdx.x >= NBUCK) {
        // ---- init path: 16 elems/thread, fp32 user||item -> fp16 table ----
        int gi = (blockIdx.x - NBUCK) * 256 + t;
        if (gi < N_ELEM / 16) {
            int base = gi * 16;
            const int UE = USER_NUM * EMB;   // 6.4M, 16-aligned
            const float4* src = (base < UE) ? (const float4*)(user + base)
                                            : (const float4*)(item + (base - UE));
            float4 f0 = src[0], f1 = src[1], f2 = src[2], f3 = src[3];
            union { int4 v; __half2 h[4]; } a, b;
            a.h[0] = __float22half2_rn(make_float2(f0.x, f0.y));
            a.h[1] = __float22half2_rn(make_float2(f0.z, f0.w));
            a.h[2] = __float22half2_rn(make_float2(f1.x, f1.y));
            a.h[3] = __float22half2_rn(make_float2(f1.z, f1.w));
            b.h[0] = __float22half2_rn(make_float2(f2.x, f2.y));
            b.h[1] = __float22half2_rn(make_float2(f2.z, f2.w));
            b.h[2] = __float22half2_rn(make_float2(f3.x, f3.y));
            b.h[3] = __float22half2_rn(make_float2(f3.z, f3.w));
            ((int4*)(emb16 + base))[0] = a.v;
            ((int4*)(emb16 + base))[1] = b.v;
        }
        return;
    }

    // ---- place path ----
    int b = blockIdx.x;
    int nrec = chunkcur[b] * 8;
    const int2* src = tmp + (size_t)b * CAP;

    for (int i = t; i < 1024; i += 256) shist[i] = 0;
    __syncthreads();
    for (int j = t; j < nrec; j += 256) {
        int x = src[j].x;
        if (x != -1) atomicAdd(&shist[x >> 18], 1);
    }
    __syncthreads();
    int h0 = shist[4 * t], h1 = shist[4 * t + 1], h2 = shist[4 * t + 2], h3 = shist[4 * t + 3];
    int sum = h0 + h1 + h2 + h3;
    swave[t] = sum;
    __syncthreads();
    for (int off = 1; off < 256; off <<= 1) {
        int u = (t >= off) ? swave[t - off] : 0;
        __syncthreads();
        swave[t] += u;
        __syncthreads();
    }
    int base = swave[t] - sum;
    __syncthreads();
    shist[4 * t]     = base;
    shist[4 * t + 1] = base + h0;
    shist[4 * t + 2] = base + h0 + h1;
    shist[4 * t + 3] = base + h0 + h1 + h2;
    __syncthreads();
    int bb = bucket_base[b];
    for (int i = t; i < 1024; i += 256) {
        int idx = b * 1024 + i;
        if (idx < N_NODES) row_ptr[idx] = bb + shist[i];
    }
    __syncthreads();
    for (int j = t; j < nrec; j += 256) {
        int2 rec = src[j];
        if (rec.x != -1) {
            int lp = atomicAdd(&shist[rec.x >> 18], 1);
            sstage[lp] = make_int2(rec.x & 0x3FFFF, rec.y);
        }
    }
    __syncthreads();
    int cnt = bucket_base[b + 1] - bb;
    for (int j = t; j < cnt; j += 256)
        edges[bb + j] = sstage[j];
}

// ---------------- fused SpMM: quarter-wave (16 lanes) per row, ILP-8 ----------------
// Lane l owns dims [4l, 4l+4). MODE 0: cur_out = acc (fp16).
// MODE 1 (last layer): out = emb16[r] + cur1[r] + in16[r] + acc (fp32 store).
template <int MODE>
__global__ __launch_bounds__(256) void spmm_kernel(
    const int* __restrict__ row_ptr, const int2* __restrict__ edges,
    const __half* __restrict__ in16, const __half* __restrict__ emb16,
    const __half* __restrict__ cur1,
    float* __restrict__ out, __half* __restrict__ cur_out)
{
    int t = blockIdx.x * blockDim.x + threadIdx.x;
    int r = t >> 4;
    int l = t & 15;
    if (r >= N_NODES) return;
    int start = row_ptr[r];
    int end   = row_ptr[r + 1];
    int idx   = r * EMB + 4 * l;

    // prefetch epilogue terms (latency hides under the gather loop)
    union { int2 i; __half2 h[2]; } pe, p1, p2;
    if (MODE == 1) {
        pe.i = *(const int2*)(emb16 + idx);
        p1.i = *(const int2*)(cur1 + idx);
        p2.i = *(const int2*)(in16 + idx);
    }

    float ax = 0.f, ay = 0.f, az = 0.f, aw = 0.f;
    for (int j = start; j < end; j += 8) {
        int2 e[8];
#pragma unroll
        for (int k = 0; k < 8; ++k) e[k] = edges[j + k];   // pad-read past end ok
#pragma unroll
        for (int k = 0; k < 8; ++k) {
            bool ok = (j + k < end);
            int   c = ok ? e[k].x : 0;
            float v = ok ? __int_as_float(e[k].y) : 0.0f;
            union { int2 i; __half2 h[2]; } g;
            g.i = *(const int2*)(in16 + c * EMB + 4 * l);
            float2 x0 = __half22float2(g.h[0]);
            float2 x1 = __half22float2(g.h[1]);
            ax += v * x0.x; ay += v * x0.y;
            az += v * x1.x; aw += v * x1.y;
        }
    }

    if (MODE == 0) {
        union { int2 i; __half2 h[2]; } o;
        o.h[0] = __float22half2_rn(make_float2(ax, ay));
        o.h[1] = __float22half2_rn(make_float2(az, aw));
        *(int2*)(cur_out + idx) = o.i;
    } else {
        float2 e0 = __half22float2(pe.h[0]), e1 = __half22float2(pe.h[1]);
        float2 c0 = __half22float2(p1.h[0]), c1 = __half22float2(p1.h[1]);
        float2 d0 = __half22float2(p2.h[0]), d1 = __half22float2(p2.h[1]);
        float4 o = make_float4(e0.x + c0.x + d0.x + ax,
                               e0.y + c0.y + d0.y + ay,
                               e1.x + c1.x + d1.x + az,
                               e1.y + c1.y + d1.y + aw);
        *(float4*)(out + idx) = o;
    }
}

extern "C" void kernel_launch(void* const* d_in, const int* in_sizes, int n_in,
                              void* d_out, int out_size, void* d_ws, size_t ws_size,
                              hipStream_t stream) {
    const float* user = (const float*)d_in[0];
    const float* item = (const float*)d_in[1];
    const int*   rows = (const int*)d_in[2];
    const int*   cols = (const int*)d_in[3];
    const float* vals = (const float*)d_in[4];
    float*       out  = (float*)d_out;

    // workspace layout (256B aligned), ~123 MB total
    char* p = (char*)d_ws;
    __half* emb16    = (__half*)p;  p += (size_t)N_ELEM * 2;            // 32 MB
    __half* cur1     = (__half*)p;  p += (size_t)N_ELEM * 2;            // 32 MB
    __half* cur2     = (__half*)p;  p += (size_t)N_ELEM * 2;            // 32 MB
    int2*   tmp      = (int2*)p;    p += (size_t)NBUCK * CAP * 8;       // 16.1 MB
    int2*   edges    = (int2*)p;    p += (size_t)N_EDGES * 8 + 256;     // 9.6 MB + pad
    int*    row_ptr  = (int*)p;     p += 1000448;                       // 250001*4 padded
    int*    bucket_base = (int*)p;  p += 1024;
    int*    bucket_cnt  = (int*)p;  p += 1024;                          // memset
    int*    chunkcur    = (int*)p;  p += 1024;                          // memset

    hipMemsetAsync(bucket_cnt, 0, 2048, stream);   // bucket_cnt + chunkcur

    bin_kernel<<<NBLK1, 256, 0, stream>>>(rows, cols, vals, chunkcur, bucket_cnt, tmp);
    scan245_kernel<<<1, 256, 0, stream>>>(bucket_cnt, bucket_base, row_ptr);
    place_init_kernel<<<NBUCK + INIT_BLOCKS, 256, 0, stream>>>(
        chunkcur, bucket_base, tmp, row_ptr, edges, user, item, emb16);

    const int spmm_blocks = (N_NODES * 16 + 255) / 256;   // 15625
    spmm_kernel<0><<<spmm_blocks, 256, 0, stream>>>(row_ptr, edges, emb16, emb16, cur1, out, cur1);
    spmm_kernel<0><<<spmm_blocks, 256, 0, stream>>>(row_ptr, edges, cur1, emb16, cur1, out, cur2);
    spmm_kernel<1><<<spmm_blocks, 256, 0, stream>>>(row_ptr, edges, cur2, emb16, cur1, out, nullptr);
}